// Round 4
// baseline (951.845 us; speedup 1.0000x reference)
//
#include <hip/hip_runtime.h>
#include <math.h>

#define PLANE  9216       // 96*96
#define PLANE4 2304       // PLANE/4
#define VOL    884736     // 96^3
#define VOL4   221184     // VOL/4
#define NC     4
#define K      7
#define HSR    3
#define SEGZ   8
#define NSEGZ  12         // 96/SEGZ
#define YT     12         // y-tile interior rows for fused y+x kernels
#define YTH    (YT + 6)   // with halo = 18
#define NSLOT  9          // YT*96/128
#define LIN_N  (YTH * 96) // 1728
#define MID_N  (YT * 96)  // 1152

__device__ __forceinline__ float4 f4zero() { return make_float4(0.f, 0.f, 0.f, 0.f); }
__device__ __forceinline__ float4 f4fma(float t, float4 a, float4 s) {
    s.x = fmaf(t, a.x, s.x); s.y = fmaf(t, a.y, s.y);
    s.z = fmaf(t, a.z, s.z); s.w = fmaf(t, a.w, s.w);
    return s;
}
__device__ __forceinline__ float4 f4fmasq(float t, float4 a, float4 s) {
    s.x = fmaf(t, a.x * a.x, s.x); s.y = fmaf(t, a.y * a.y, s.y);
    s.z = fmaf(t, a.z * a.z, s.z); s.w = fmaf(t, a.w * a.w, s.w);
    return s;
}
__device__ __forceinline__ float4 f4mul(float4 a, float4 b) {
    return make_float4(a.x * b.x, a.y * b.y, a.z * b.z, a.w * b.w);
}

// ---------------- tables: 1D taps + boundary sums ----------------
__global__ void tables_kernel(const float* __restrict__ sigma2,
                              const float* __restrict__ sigma3,
                              float* __restrict__ taps2, float* __restrict__ taps3,
                              float* __restrict__ B2, float* __restrict__ B3)
{
    int t = threadIdx.x;
    if (t < 2 * NC) {
        int c = t % NC;
        const float* sig = (t < NC) ? sigma2 : sigma3;
        float* taps = (t < NC) ? taps2 : taps3;
        float sv = sig[c];
        float s2 = sv * sv;
        float w[K];
        float sum = 0.f;
        for (int j = 0; j < K; j++) {
            float d = (float)(j - HSR);
            w[j] = expf(-d * d / (2.f * s2));
            sum += w[j];
        }
        float inv = 1.f / sum;   // sum3d = sum^3; per-axis norm by sum reproduces it
        for (int j = 0; j < K; j++) taps[c * K + j] = w[j] * inv;
    }
    __syncthreads();
    for (int i = t; i < NC * 96; i += blockDim.x) {
        int c = i / 96, p = i % 96;
        float s2v = 0.f, s3v = 0.f;
        for (int j = 0; j < K; j++) {
            int q = p + j - HSR;
            if (q >= 0 && q < 96) { s2v += taps2[c * K + j]; s3v += taps3[c * K + j]; }
        }
        B2[i] = s2v;
        B3[i] = s3v;
    }
}

// ---------------- initial softmax over C (float4) ----------------
__global__ __launch_bounds__(256) void softmax0_kernel(const float* __restrict__ o,
                                                       const float* __restrict__ eta,
                                                       float* __restrict__ u)
{
    int i = blockIdx.x * 256 + threadIdx.x;
    const float4* O = (const float4*)o;
    float4* U = (float4*)u;
    float inv_eta = 1.f / eta[0];
    float4 a0 = O[i], a1 = O[i + VOL4], a2 = O[i + 2 * VOL4], a3 = O[i + 3 * VOL4];
#define SM_COMP(f)                                                              \
    {                                                                           \
        float b0 = a0.f * inv_eta, b1 = a1.f * inv_eta;                         \
        float b2 = a2.f * inv_eta, b3 = a3.f * inv_eta;                         \
        float m = fmaxf(fmaxf(b0, b1), fmaxf(b2, b3));                          \
        float e0 = __expf(b0 - m), e1 = __expf(b1 - m);                         \
        float e2 = __expf(b2 - m), e3 = __expf(b3 - m);                         \
        float inv = 1.f / (e0 + e1 + e2 + e3);                                  \
        a0.f = e0 * inv; a1.f = e1 * inv; a2.f = e2 * inv; a3.f = e3 * inv;     \
    }
    SM_COMP(x) SM_COMP(y) SM_COMP(z) SM_COMP(w)
    U[i] = a0; U[i + VOL4] = a1; U[i + 2 * VOL4] = a2; U[i + 3 * VOL4] = a3;
}

// ---------------- K1: z-conv of {u*I, u (ker_lif), u (ker)}, float4 ----------------
__global__ __launch_bounds__(256) void pass1_z(const float* __restrict__ u,
                                               const float* __restrict__ I,
                                               const float* __restrict__ taps2,
                                               const float* __restrict__ taps3,
                                               float* __restrict__ a0, float* __restrict__ a1,
                                               float* __restrict__ a2)
{
    int p4 = blockIdx.x * 256 + threadIdx.x;   // float4 index within plane
    int s  = blockIdx.y;
    int c  = blockIdx.z;
    int z0 = s * SEGZ;
    const float4* ub = (const float4*)(u + (size_t)c * VOL) + p4;
    const float4* Ib = (const float4*)I + p4;
    float t3[K], t2[K];
#pragma unroll
    for (int j = 0; j < K; j++) { t3[j] = taps3[c * K + j]; t2[j] = taps2[c * K + j]; }
    float4 wu[K], wui[K];
#pragma unroll
    for (int j = 0; j < K - 1; j++) {
        int z = z0 + j - HSR;
        float4 uv = f4zero(), iv = f4zero();
        if (z >= 0 && z < 96) { uv = ub[z * PLANE4]; iv = Ib[z * PLANE4]; }
        wu[j] = uv; wui[j] = f4mul(uv, iv);
    }
    float4* o0 = (float4*)(a0 + (size_t)c * VOL) + p4;
    float4* o1 = (float4*)(a1 + (size_t)c * VOL) + p4;
    float4* o2 = (float4*)(a2 + (size_t)c * VOL) + p4;
    for (int k = 0; k < SEGZ; k++) {
        int z = z0 + k, zl = z + HSR;
        float4 uv = f4zero(), iv = f4zero();
        if (zl < 96) { uv = ub[zl * PLANE4]; iv = Ib[zl * PLANE4]; }
        wu[K - 1] = uv; wui[K - 1] = f4mul(uv, iv);
        float4 s0 = f4zero(), s1 = f4zero(), s2 = f4zero();
#pragma unroll
        for (int j = 0; j < K; j++) {
            s0 = f4fma(t3[j], wui[j], s0);
            s1 = f4fma(t3[j], wu[j], s1);
            s2 = f4fma(t2[j], wu[j], s2);
        }
        o0[z * PLANE4] = s0;
        o1[z * PLANE4] = s1;
        o2[z * PLANE4] = s2;
#pragma unroll
        for (int j = 0; j < K - 1; j++) { wu[j] = wu[j + 1]; wui[j] = wui[j + 1]; }
    }
}

// ---------------- K2: fused y+x conv of 3 fields -> Cn, q ----------------
// Single load phase (3 fields, float4, high MLP), 2 barriers total.
__global__ __launch_bounds__(128) void pass2_yx(const float* __restrict__ a0,
                                                const float* __restrict__ a1,
                                                const float* __restrict__ a2,
                                                const float* __restrict__ taps2,
                                                const float* __restrict__ taps3,
                                                const float* __restrict__ B2,
                                                float* __restrict__ Cn, float* __restrict__ q)
{
    __shared__ float lin[3][LIN_N];
    __shared__ float mid[3][MID_N];
    int yt = blockIdx.x, z = blockIdx.y, c = blockIdx.z;
    int y0 = yt * YT, tid = threadIdx.x;
    size_t base = (size_t)c * VOL + (size_t)z * PLANE;
    int start4 = (y0 - HSR) * 24;   // float4 index of tile start within plane
    {
        const float4* g0 = (const float4*)(a0 + base);
        const float4* g1 = (const float4*)(a1 + base);
        const float4* g2 = (const float4*)(a2 + base);
        float4* l0 = (float4*)lin[0];
        float4* l1 = (float4*)lin[1];
        float4* l2 = (float4*)lin[2];
#pragma unroll
        for (int i4 = tid; i4 < LIN_N / 4; i4 += 128) {
            int gi = start4 + i4;
            bool ok = (gi >= 0 && gi < PLANE4);
            float4 v0 = ok ? g0[gi] : f4zero();
            float4 v1 = ok ? g1[gi] : f4zero();
            float4 v2 = ok ? g2[gi] : f4zero();
            l0[i4] = v0; l1[i4] = v1; l2[i4] = v2;
        }
    }
    float t3[K], t2[K];
#pragma unroll
    for (int j = 0; j < K; j++) { t3[j] = taps3[c * K + j]; t2[j] = taps2[c * K + j]; }
    __syncthreads();
#pragma unroll
    for (int slot = 0; slot < NSLOT; slot++) {
        int m = tid + slot * 128;
        int r = m / 96, x = m - r * 96;
        float sA = 0.f, sB = 0.f, sC = 0.f;
#pragma unroll
        for (int j = 0; j < K; j++) {
            int off = (r + j) * 96 + x;
            sA += t3[j] * lin[0][off];
            sB += t3[j] * lin[1][off];
            sC += t2[j] * lin[2][off];
        }
        mid[0][m] = sA; mid[1][m] = sB; mid[2][m] = sC;
    }
    __syncthreads();
    float Bz = B2[c * 96 + z];
#pragma unroll
    for (int slot = 0; slot < NSLOT; slot++) {
        int m = tid + slot * 128;
        int r = m / 96, x = m - r * 96;
        int y = y0 + r;
        float sA = 0.f, sB = 0.f, sC = 0.f;
#pragma unroll
        for (int j = 0; j < K; j++) {
            int xx = x + j - HSR;
            if (xx >= 0 && xx < 96) {
                sA += t3[j] * mid[0][r * 96 + xx];
                sB += t3[j] * mid[1][r * 96 + xx];
                sC += t2[j] * mid[2][r * 96 + xx];
            }
        }
        float Cnv = (sA + 1e-6f) / (sB + 1e-6f);
        float qv = Bz * B2[c * 96 + y] * B2[c * 96 + x] - 2.f * sC;
        Cn[base + y * 96 + x] = Cnv;
        q[base + y * 96 + x]  = qv;
    }
}

// ---------------- K3: z-conv of {Cn, Cn^2}, float4 ----------------
__global__ __launch_bounds__(256) void pass4_z(const float* __restrict__ Cn,
                                               const float* __restrict__ taps3,
                                               float* __restrict__ b0, float* __restrict__ b1)
{
    int p4 = blockIdx.x * 256 + threadIdx.x;
    int s  = blockIdx.y;
    int c  = blockIdx.z;
    int z0 = s * SEGZ;
    const float4* ib = (const float4*)(Cn + (size_t)c * VOL) + p4;
    float t3[K];
#pragma unroll
    for (int j = 0; j < K; j++) t3[j] = taps3[c * K + j];
    float4 w[K];
#pragma unroll
    for (int j = 0; j < K - 1; j++) {
        int z = z0 + j - HSR;
        float4 v = f4zero();
        if (z >= 0 && z < 96) v = ib[z * PLANE4];
        w[j] = v;
    }
    float4* o0 = (float4*)(b0 + (size_t)c * VOL) + p4;
    float4* o1 = (float4*)(b1 + (size_t)c * VOL) + p4;
    for (int k = 0; k < SEGZ; k++) {
        int z = z0 + k, zl = z + HSR;
        float4 v = f4zero();
        if (zl < 96) v = ib[zl * PLANE4];
        w[K - 1] = v;
        float4 s0 = f4zero(), s1 = f4zero();
#pragma unroll
        for (int j = 0; j < K; j++) {
            s0 = f4fma(t3[j], w[j], s0);
            s1 = f4fmasq(t3[j], w[j], s1);
        }
        o0[z * PLANE4] = s0;
        o1[z * PLANE4] = s1;
#pragma unroll
        for (int j = 0; j < K - 1; j++) w[j] = w[j + 1];
    }
}

// ---------------- K4: fused y+x conv of {cz0,cz1} (one channel) + Lif + arg ----------------
__global__ __launch_bounds__(128) void pass5_yx(const float* __restrict__ cz0,
                                                const float* __restrict__ cz1,
                                                const float* __restrict__ q,
                                                const float* __restrict__ o,
                                                const float* __restrict__ I,
                                                const float* __restrict__ taps3,
                                                const float* __restrict__ B3,
                                                const float* __restrict__ eta,
                                                const float* __restrict__ lam,
                                                const float* __restrict__ mu,
                                                float* __restrict__ argb)
{
    __shared__ float lin[2][LIN_N];
    __shared__ float mid[2][MID_N];
    int yt = blockIdx.x, z = blockIdx.y, c = blockIdx.z;
    int y0 = yt * YT, tid = threadIdx.x;
    size_t base = (size_t)c * VOL + (size_t)z * PLANE;
    int start4 = (y0 - HSR) * 24;
    {
        const float4* g0 = (const float4*)(cz0 + base);
        const float4* g1 = (const float4*)(cz1 + base);
        float4* l0 = (float4*)lin[0];
        float4* l1 = (float4*)lin[1];
#pragma unroll
        for (int i4 = tid; i4 < LIN_N / 4; i4 += 128) {
            int gi = start4 + i4;
            bool ok = (gi >= 0 && gi < PLANE4);
            float4 v0 = ok ? g0[gi] : f4zero();
            float4 v1 = ok ? g1[gi] : f4zero();
            l0[i4] = v0; l1[i4] = v1;
        }
    }
    float t3[K];
#pragma unroll
    for (int j = 0; j < K; j++) t3[j] = taps3[c * K + j];
    __syncthreads();
#pragma unroll
    for (int slot = 0; slot < NSLOT; slot++) {
        int m = tid + slot * 128;
        int r = m / 96, x = m - r * 96;
        float sA = 0.f, sB = 0.f;
#pragma unroll
        for (int j = 0; j < K; j++) {
            int off = (r + j) * 96 + x;
            sA += t3[j] * lin[0][off];
            sB += t3[j] * lin[1][off];
        }
        mid[0][m] = sA; mid[1][m] = sB;
    }
    __syncthreads();
    float inv_eta = 1.f / eta[0];
    float lamv = lam[0], muv = mu[0];
    float Bz = B3[c * 96 + z];
#pragma unroll
    for (int slot = 0; slot < NSLOT; slot++) {
        int m = tid + slot * 128;
        int r = m / 96, x = m - r * 96;
        int y = y0 + r;
        float d0 = 0.f, d1 = 0.f;
#pragma unroll
        for (int j = 0; j < K; j++) {
            int xx = x + j - HSR;
            if (xx >= 0 && xx < 96) {
                d0 += t3[j] * mid[0][r * 96 + xx];
                d1 += t3[j] * mid[1][r * 96 + xx];
            }
        }
        int v = z * PLANE + y * 96 + x;
        float Iv = I[v];
        float cones = Bz * B3[c * 96 + y] * B3[c * 96 + x];
        float Lif = d1 - 2.f * Iv * d0 + Iv * Iv * cones;
        argb[base + y * 96 + x] = (o[c * VOL + v] - muv * Lif - lamv * q[c * VOL + v]) * inv_eta;
    }
}

// ---------------- K5: channel softmax of arg -> u (float4) ----------------
__global__ __launch_bounds__(256) void pass6_softmax(const float* __restrict__ argb,
                                                     float* __restrict__ u)
{
    int i = blockIdx.x * 256 + threadIdx.x;
    const float4* A = (const float4*)argb;
    float4* U = (float4*)u;
    float4 a0 = A[i], a1 = A[i + VOL4], a2 = A[i + 2 * VOL4], a3 = A[i + 3 * VOL4];
#define SM2_COMP(f)                                                             \
    {                                                                           \
        float m = fmaxf(fmaxf(a0.f, a1.f), fmaxf(a2.f, a3.f));                  \
        float e0 = __expf(a0.f - m), e1 = __expf(a1.f - m);                     \
        float e2 = __expf(a2.f - m), e3 = __expf(a3.f - m);                     \
        float inv = 1.f / (e0 + e1 + e2 + e3);                                  \
        a0.f = e0 * inv; a1.f = e1 * inv; a2.f = e2 * inv; a3.f = e3 * inv;     \
    }
    SM2_COMP(x) SM2_COMP(y) SM2_COMP(z) SM2_COMP(w)
    U[i] = a0; U[i + VOL4] = a1; U[i + 2 * VOL4] = a2; U[i + 3 * VOL4] = a3;
}

extern "C" void kernel_launch(void* const* d_in, const int* in_sizes, int n_in,
                              void* d_out, int out_size, void* d_ws, size_t ws_size,
                              hipStream_t stream)
{
    const float* o      = (const float*)d_in[0];
    const float* I      = (const float*)d_in[1];
    const float* sigma2 = (const float*)d_in[2];
    const float* sigma3 = (const float*)d_in[3];
    const float* eta    = (const float*)d_in[4];
    const float* lam    = (const float*)d_in[5];
    const float* mu     = (const float*)d_in[6];
    float* u = (float*)d_out;

    float* wsf = (float*)d_ws;
    float* taps2 = wsf;              // 28 floats
    float* taps3 = wsf + 32;
    float* B2    = wsf + 64;         // 384 floats
    float* B3    = wsf + 64 + NC * 96;
    float* buf   = wsf + 1024;
    const size_t VCs = (size_t)NC * VOL;
    float* a0 = buf;                 // z-conv outs; a0 reused as arg buffer
    float* a1 = buf + VCs;
    float* a2 = buf + 2 * VCs;
    float* Cn = buf + 3 * VCs;
    float* qb = buf + 4 * VCs;
    float* c0 = buf + 5 * VCs;       // z-conv of Cn, Cn^2
    float* c1 = buf + 6 * VCs;

    const dim3 gridZ(PLANE4 / 256, NSEGZ, NC);  // 9 x 12 x 4 = 432 blocks (256t)
    const dim3 gridYX(96 / YT, 96, NC);         // 8 x 96 x 4 = 3072 blocks (128t)
    const int gridV4 = VOL4 / 256;              // 864

    tables_kernel<<<1, 512, 0, stream>>>(sigma2, sigma3, taps2, taps3, B2, B3);
    softmax0_kernel<<<gridV4, 256, 0, stream>>>(o, eta, u);
    for (int it = 0; it < 10; it++) {
        pass1_z<<<gridZ, 256, 0, stream>>>(u, I, taps2, taps3, a0, a1, a2);
        pass2_yx<<<gridYX, 128, 0, stream>>>(a0, a1, a2, taps2, taps3, B2, Cn, qb);
        pass4_z<<<gridZ, 256, 0, stream>>>(Cn, taps3, c0, c1);
        pass5_yx<<<gridYX, 128, 0, stream>>>(c0, c1, qb, o, I, taps3, B3,
                                             eta, lam, mu, a0);
        pass6_softmax<<<gridV4, 256, 0, stream>>>(a0, u);
    }
}

// Round 5
// 704.573 us; speedup vs baseline: 1.3510x; 1.3510x over previous
//
#include <hip/hip_runtime.h>
#include <math.h>

#define PLANE  9216       // 96*96
#define PLANE4 2304       // PLANE/4
#define VOL    884736     // 96^3
#define VOL4   221184     // VOL/4
#define NC     4
#define K      7
#define HSR    3
#define SEGZ   8
#define NSEGZ  12         // 96/SEGZ

// fused y+x kernels: 192 threads = 16 rows x 12 chunks of 8 x
#define YT     16
#define YTH    22         // YT + 6 halo rows
#define TPBYX  192
#define LINW   100        // lin row stride (dwords); 100%32=4 breaks bank aliasing
#define MIDW   108        // mid row stride: 4 pad + 96 + 4 pad (+4 spare); 108%32=12
#define NF4    528        // YTH*96/4 float4 loads per field

__device__ __forceinline__ float4 f4zero() { return make_float4(0.f, 0.f, 0.f, 0.f); }
__device__ __forceinline__ float4 f4fma(float t, float4 a, float4 s) {
    s.x = fmaf(t, a.x, s.x); s.y = fmaf(t, a.y, s.y);
    s.z = fmaf(t, a.z, s.z); s.w = fmaf(t, a.w, s.w);
    return s;
}
__device__ __forceinline__ float4 f4fmasq(float t, float4 a, float4 s) {
    s.x = fmaf(t, a.x * a.x, s.x); s.y = fmaf(t, a.y * a.y, s.y);
    s.z = fmaf(t, a.z * a.z, s.z); s.w = fmaf(t, a.w * a.w, s.w);
    return s;
}
__device__ __forceinline__ float4 f4mul(float4 a, float4 b) {
    return make_float4(a.x * b.x, a.y * b.y, a.z * b.z, a.w * b.w);
}

// ---------------- tables: 1D taps + boundary sums ----------------
__global__ void tables_kernel(const float* __restrict__ sigma2,
                              const float* __restrict__ sigma3,
                              float* __restrict__ taps2, float* __restrict__ taps3,
                              float* __restrict__ B2, float* __restrict__ B3)
{
    int t = threadIdx.x;
    if (t < 2 * NC) {
        int c = t % NC;
        const float* sig = (t < NC) ? sigma2 : sigma3;
        float* taps = (t < NC) ? taps2 : taps3;
        float sv = sig[c];
        float s2 = sv * sv;
        float w[K];
        float sum = 0.f;
        for (int j = 0; j < K; j++) {
            float d = (float)(j - HSR);
            w[j] = expf(-d * d / (2.f * s2));
            sum += w[j];
        }
        float inv = 1.f / sum;   // sum3d = sum^3; per-axis norm by sum reproduces it
        for (int j = 0; j < K; j++) taps[c * K + j] = w[j] * inv;
    }
    __syncthreads();
    for (int i = t; i < NC * 96; i += blockDim.x) {
        int c = i / 96, p = i % 96;
        float s2v = 0.f, s3v = 0.f;
        for (int j = 0; j < K; j++) {
            int q = p + j - HSR;
            if (q >= 0 && q < 96) { s2v += taps2[c * K + j]; s3v += taps3[c * K + j]; }
        }
        B2[i] = s2v;
        B3[i] = s3v;
    }
}

// ---------------- initial softmax over C (float4) ----------------
__global__ __launch_bounds__(256) void softmax0_kernel(const float* __restrict__ o,
                                                       const float* __restrict__ eta,
                                                       float* __restrict__ u)
{
    int i = blockIdx.x * 256 + threadIdx.x;
    const float4* O = (const float4*)o;
    float4* U = (float4*)u;
    float inv_eta = 1.f / eta[0];
    float4 a0 = O[i], a1 = O[i + VOL4], a2 = O[i + 2 * VOL4], a3 = O[i + 3 * VOL4];
#define SM_COMP(f)                                                              \
    {                                                                           \
        float b0 = a0.f * inv_eta, b1 = a1.f * inv_eta;                         \
        float b2 = a2.f * inv_eta, b3 = a3.f * inv_eta;                         \
        float m = fmaxf(fmaxf(b0, b1), fmaxf(b2, b3));                          \
        float e0 = __expf(b0 - m), e1 = __expf(b1 - m);                         \
        float e2 = __expf(b2 - m), e3 = __expf(b3 - m);                         \
        float inv = 1.f / (e0 + e1 + e2 + e3);                                  \
        a0.f = e0 * inv; a1.f = e1 * inv; a2.f = e2 * inv; a3.f = e3 * inv;     \
    }
    SM_COMP(x) SM_COMP(y) SM_COMP(z) SM_COMP(w)
    U[i] = a0; U[i + VOL4] = a1; U[i + 2 * VOL4] = a2; U[i + 3 * VOL4] = a3;
}

// ---------------- K1: z-conv of {u*I, u (ker_lif), u (ker)}, float4 ----------------
__global__ __launch_bounds__(256) void pass1_z(const float* __restrict__ u,
                                               const float* __restrict__ I,
                                               const float* __restrict__ taps2,
                                               const float* __restrict__ taps3,
                                               float* __restrict__ a0, float* __restrict__ a1,
                                               float* __restrict__ a2)
{
    int p4 = blockIdx.x * 256 + threadIdx.x;   // float4 index within plane
    int s  = blockIdx.y;
    int c  = blockIdx.z;
    int z0 = s * SEGZ;
    const float4* ub = (const float4*)(u + (size_t)c * VOL) + p4;
    const float4* Ib = (const float4*)I + p4;
    float t3[K], t2[K];
#pragma unroll
    for (int j = 0; j < K; j++) { t3[j] = taps3[c * K + j]; t2[j] = taps2[c * K + j]; }
    float4 wu[K], wui[K];
#pragma unroll
    for (int j = 0; j < K - 1; j++) {
        int z = z0 + j - HSR;
        float4 uv = f4zero(), iv = f4zero();
        if (z >= 0 && z < 96) { uv = ub[z * PLANE4]; iv = Ib[z * PLANE4]; }
        wu[j] = uv; wui[j] = f4mul(uv, iv);
    }
    float4* o0 = (float4*)(a0 + (size_t)c * VOL) + p4;
    float4* o1 = (float4*)(a1 + (size_t)c * VOL) + p4;
    float4* o2 = (float4*)(a2 + (size_t)c * VOL) + p4;
    for (int k = 0; k < SEGZ; k++) {
        int z = z0 + k, zl = z + HSR;
        float4 uv = f4zero(), iv = f4zero();
        if (zl < 96) { uv = ub[zl * PLANE4]; iv = Ib[zl * PLANE4]; }
        wu[K - 1] = uv; wui[K - 1] = f4mul(uv, iv);
        float4 s0 = f4zero(), s1 = f4zero(), s2 = f4zero();
#pragma unroll
        for (int j = 0; j < K; j++) {
            s0 = f4fma(t3[j], wui[j], s0);
            s1 = f4fma(t3[j], wu[j], s1);
            s2 = f4fma(t2[j], wu[j], s2);
        }
        o0[z * PLANE4] = s0;
        o1[z * PLANE4] = s1;
        o2[z * PLANE4] = s2;
#pragma unroll
        for (int j = 0; j < K - 1; j++) { wu[j] = wu[j + 1]; wui[j] = wui[j + 1]; }
    }
}

// ---------------- K2: fused y+x conv of 3 fields -> Cn, q ----------------
// 192t = 16 rows x 12 chunks of 8x. b128 LDS, mids in registers, 2 barriers.
__global__ __launch_bounds__(TPBYX) void pass2_yx(const float* __restrict__ a0,
                                                  const float* __restrict__ a1,
                                                  const float* __restrict__ a2,
                                                  const float* __restrict__ taps2,
                                                  const float* __restrict__ taps3,
                                                  const float* __restrict__ B2,
                                                  float* __restrict__ Cn,
                                                  float* __restrict__ q)
{
    __shared__ float lin[3][YTH * LINW];
    __shared__ float mid[3][YT * MIDW];
    int yt = blockIdx.x, z = blockIdx.y, c = blockIdx.z;
    int y0 = yt * YT, tid = threadIdx.x;
    size_t base = (size_t)c * VOL + (size_t)z * PLANE;
    // ---- load phase: all 3 fields, float4 ----
    {
        const float4* g0 = (const float4*)(a0 + base);
        const float4* g1 = (const float4*)(a1 + base);
        const float4* g2 = (const float4*)(a2 + base);
#pragma unroll
        for (int i4 = tid; i4 < NF4; i4 += TPBYX) {
            int r = i4 / 24, k = i4 - r * 24;
            int gy = y0 - HSR + r;
            bool ok = (gy >= 0 && gy < 96);
            int gi = gy * 24 + k;
            float4 v0 = ok ? g0[gi] : f4zero();
            float4 v1 = ok ? g1[gi] : f4zero();
            float4 v2 = ok ? g2[gi] : f4zero();
            int li = r * LINW + k * 4;
            *(float4*)&lin[0][li] = v0;
            *(float4*)&lin[1][li] = v1;
            *(float4*)&lin[2][li] = v2;
        }
    }
    // zero mid x-pads (written once, never overwritten)
    if (tid < 128) {
        int r = tid >> 3, p = tid & 7;
        int idx = r * MIDW + (p < 4 ? p : 96 + p);   // 0..3 and 100..103
        mid[0][idx] = 0.f; mid[1][idx] = 0.f; mid[2][idx] = 0.f;
    }
    float t3[K], t2[K];
#pragma unroll
    for (int j = 0; j < K; j++) { t3[j] = taps3[c * K + j]; t2[j] = taps2[c * K + j]; }
    __syncthreads();
    int r  = tid / 12;
    int xb = (tid - r * 12) * 8;
    // ---- y-conv: 7 taps x 2 b128 per field; mids in regs -> 2 b128 writes ----
#pragma unroll
    for (int f = 0; f < 3; f++) {
        const float* tp = (f < 2) ? t3 : t2;
        float4 mA = f4zero(), mB = f4zero();
#pragma unroll
        for (int j = 0; j < K; j++) {
            const float4* lp = (const float4*)&lin[f][(r + j) * LINW + xb];
            mA = f4fma(tp[j], lp[0], mA);
            mB = f4fma(tp[j], lp[1], mB);
        }
        float4* mp = (float4*)&mid[f][r * MIDW + 4 + xb];
        mp[0] = mA; mp[1] = mB;
    }
    __syncthreads();
    // ---- x-conv: 4 aligned b128 window reads per field, 56 reg FMAs ----
    float outA[8], outB[8], outC[8];
    {
        float wf[16];
#pragma unroll
        for (int f = 0; f < 3; f++) {
            const float* tp = (f < 2) ? t3 : t2;
            const float4* wp = (const float4*)&mid[f][r * MIDW + xb];
            *(float4*)&wf[0]  = wp[0];
            *(float4*)&wf[4]  = wp[1];
            *(float4*)&wf[8]  = wp[2];
            *(float4*)&wf[12] = wp[3];
            float* dst = (f == 0) ? outA : (f == 1) ? outB : outC;
#pragma unroll
            for (int k = 0; k < 8; k++) {
                float s = 0.f;
#pragma unroll
                for (int j = 0; j < K; j++) s = fmaf(tp[j], wf[k + j + 1], s);
                dst[k] = s;
            }
        }
    }
    // ---- epilogue: Cn, q ----
    int y = y0 + r;
    float Bz = B2[c * 96 + z];
    float By = B2[c * 96 + y];
    float Bx[8];
    {
        const float4* bx = (const float4*)&B2[c * 96 + xb];
        *(float4*)&Bx[0] = bx[0];
        *(float4*)&Bx[4] = bx[1];
    }
    float co[8], qo[8];
#pragma unroll
    for (int k = 0; k < 8; k++) {
        co[k] = (outA[k] + 1e-6f) / (outB[k] + 1e-6f);
        qo[k] = fmaf(Bz * By, Bx[k], -2.f * outC[k]);
    }
    float* cp = Cn + base + y * 96 + xb;
    float* qp = q  + base + y * 96 + xb;
    *(float4*)cp       = *(float4*)&co[0];
    *(float4*)(cp + 4) = *(float4*)&co[4];
    *(float4*)qp       = *(float4*)&qo[0];
    *(float4*)(qp + 4) = *(float4*)&qo[4];
}

// ---------------- K3: z-conv of {Cn, Cn^2}, float4 ----------------
__global__ __launch_bounds__(256) void pass4_z(const float* __restrict__ Cn,
                                               const float* __restrict__ taps3,
                                               float* __restrict__ b0, float* __restrict__ b1)
{
    int p4 = blockIdx.x * 256 + threadIdx.x;
    int s  = blockIdx.y;
    int c  = blockIdx.z;
    int z0 = s * SEGZ;
    const float4* ib = (const float4*)(Cn + (size_t)c * VOL) + p4;
    float t3[K];
#pragma unroll
    for (int j = 0; j < K; j++) t3[j] = taps3[c * K + j];
    float4 w[K];
#pragma unroll
    for (int j = 0; j < K - 1; j++) {
        int z = z0 + j - HSR;
        float4 v = f4zero();
        if (z >= 0 && z < 96) v = ib[z * PLANE4];
        w[j] = v;
    }
    float4* o0 = (float4*)(b0 + (size_t)c * VOL) + p4;
    float4* o1 = (float4*)(b1 + (size_t)c * VOL) + p4;
    for (int k = 0; k < SEGZ; k++) {
        int z = z0 + k, zl = z + HSR;
        float4 v = f4zero();
        if (zl < 96) v = ib[zl * PLANE4];
        w[K - 1] = v;
        float4 s0 = f4zero(), s1 = f4zero();
#pragma unroll
        for (int j = 0; j < K; j++) {
            s0 = f4fma(t3[j], w[j], s0);
            s1 = f4fmasq(t3[j], w[j], s1);
        }
        o0[z * PLANE4] = s0;
        o1[z * PLANE4] = s1;
#pragma unroll
        for (int j = 0; j < K - 1; j++) w[j] = w[j + 1];
    }
}

// ---------------- K4: fused y+x conv of {cz0,cz1} + Lif + arg ----------------
__global__ __launch_bounds__(TPBYX) void pass5_yx(const float* __restrict__ cz0,
                                                  const float* __restrict__ cz1,
                                                  const float* __restrict__ q,
                                                  const float* __restrict__ o,
                                                  const float* __restrict__ I,
                                                  const float* __restrict__ taps3,
                                                  const float* __restrict__ B3,
                                                  const float* __restrict__ eta,
                                                  const float* __restrict__ lam,
                                                  const float* __restrict__ mu,
                                                  float* __restrict__ argb)
{
    __shared__ float lin[2][YTH * LINW];
    __shared__ float mid[2][YT * MIDW];
    int yt = blockIdx.x, z = blockIdx.y, c = blockIdx.z;
    int y0 = yt * YT, tid = threadIdx.x;
    size_t base = (size_t)c * VOL + (size_t)z * PLANE;
    {
        const float4* g0 = (const float4*)(cz0 + base);
        const float4* g1 = (const float4*)(cz1 + base);
#pragma unroll
        for (int i4 = tid; i4 < NF4; i4 += TPBYX) {
            int r = i4 / 24, k = i4 - r * 24;
            int gy = y0 - HSR + r;
            bool ok = (gy >= 0 && gy < 96);
            int gi = gy * 24 + k;
            float4 v0 = ok ? g0[gi] : f4zero();
            float4 v1 = ok ? g1[gi] : f4zero();
            int li = r * LINW + k * 4;
            *(float4*)&lin[0][li] = v0;
            *(float4*)&lin[1][li] = v1;
        }
    }
    if (tid < 128) {
        int r = tid >> 3, p = tid & 7;
        int idx = r * MIDW + (p < 4 ? p : 96 + p);
        mid[0][idx] = 0.f; mid[1][idx] = 0.f;
    }
    float t3[K];
#pragma unroll
    for (int j = 0; j < K; j++) t3[j] = taps3[c * K + j];
    __syncthreads();
    int r  = tid / 12;
    int xb = (tid - r * 12) * 8;
#pragma unroll
    for (int f = 0; f < 2; f++) {
        float4 mA = f4zero(), mB = f4zero();
#pragma unroll
        for (int j = 0; j < K; j++) {
            const float4* lp = (const float4*)&lin[f][(r + j) * LINW + xb];
            mA = f4fma(t3[j], lp[0], mA);
            mB = f4fma(t3[j], lp[1], mB);
        }
        float4* mp = (float4*)&mid[f][r * MIDW + 4 + xb];
        mp[0] = mA; mp[1] = mB;
    }
    __syncthreads();
    float d0[8], d1[8];
    {
        float wf[16];
#pragma unroll
        for (int f = 0; f < 2; f++) {
            const float4* wp = (const float4*)&mid[f][r * MIDW + xb];
            *(float4*)&wf[0]  = wp[0];
            *(float4*)&wf[4]  = wp[1];
            *(float4*)&wf[8]  = wp[2];
            *(float4*)&wf[12] = wp[3];
            float* dst = (f == 0) ? d0 : d1;
#pragma unroll
            for (int k = 0; k < 8; k++) {
                float s = 0.f;
#pragma unroll
                for (int j = 0; j < K; j++) s = fmaf(t3[j], wf[k + j + 1], s);
                dst[k] = s;
            }
        }
    }
    int y = y0 + r;
    int v = z * PLANE + y * 96 + xb;
    float inv_eta = 1.f / eta[0];
    float lamv = lam[0], muv = mu[0];
    float Bz = B3[c * 96 + z];
    float By = B3[c * 96 + y];
    float Bx[8], Ivv[8], ov[8], qv[8];
    {
        const float4* bx = (const float4*)&B3[c * 96 + xb];
        *(float4*)&Bx[0] = bx[0]; *(float4*)&Bx[4] = bx[1];
        const float4* ip = (const float4*)&I[v];
        *(float4*)&Ivv[0] = ip[0]; *(float4*)&Ivv[4] = ip[1];
        const float4* op = (const float4*)&o[(size_t)c * VOL + v];
        *(float4*)&ov[0] = op[0]; *(float4*)&ov[4] = op[1];
        const float4* qp = (const float4*)&q[(size_t)c * VOL + v];
        *(float4*)&qv[0] = qp[0]; *(float4*)&qv[4] = qp[1];
    }
    float res[8];
#pragma unroll
    for (int k = 0; k < 8; k++) {
        float Iv = Ivv[k];
        float cones = Bz * By * Bx[k];
        float Lif = d1[k] - 2.f * Iv * d0[k] + Iv * Iv * cones;
        res[k] = (ov[k] - muv * Lif - lamv * qv[k]) * inv_eta;
    }
    float* ap = argb + base + y * 96 + xb;
    *(float4*)ap       = *(float4*)&res[0];
    *(float4*)(ap + 4) = *(float4*)&res[4];
}

// ---------------- K5: channel softmax of arg -> u (float4) ----------------
__global__ __launch_bounds__(256) void pass6_softmax(const float* __restrict__ argb,
                                                     float* __restrict__ u)
{
    int i = blockIdx.x * 256 + threadIdx.x;
    const float4* A = (const float4*)argb;
    float4* U = (float4*)u;
    float4 a0 = A[i], a1 = A[i + VOL4], a2 = A[i + 2 * VOL4], a3 = A[i + 3 * VOL4];
#define SM2_COMP(f)                                                             \
    {                                                                           \
        float m = fmaxf(fmaxf(a0.f, a1.f), fmaxf(a2.f, a3.f));                  \
        float e0 = __expf(a0.f - m), e1 = __expf(a1.f - m);                     \
        float e2 = __expf(a2.f - m), e3 = __expf(a3.f - m);                     \
        float inv = 1.f / (e0 + e1 + e2 + e3);                                  \
        a0.f = e0 * inv; a1.f = e1 * inv; a2.f = e2 * inv; a3.f = e3 * inv;     \
    }
    SM2_COMP(x) SM2_COMP(y) SM2_COMP(z) SM2_COMP(w)
    U[i] = a0; U[i + VOL4] = a1; U[i + 2 * VOL4] = a2; U[i + 3 * VOL4] = a3;
}

extern "C" void kernel_launch(void* const* d_in, const int* in_sizes, int n_in,
                              void* d_out, int out_size, void* d_ws, size_t ws_size,
                              hipStream_t stream)
{
    const float* o      = (const float*)d_in[0];
    const float* I      = (const float*)d_in[1];
    const float* sigma2 = (const float*)d_in[2];
    const float* sigma3 = (const float*)d_in[3];
    const float* eta    = (const float*)d_in[4];
    const float* lam    = (const float*)d_in[5];
    const float* mu     = (const float*)d_in[6];
    float* u = (float*)d_out;

    float* wsf = (float*)d_ws;
    float* taps2 = wsf;              // 28 floats
    float* taps3 = wsf + 32;
    float* B2    = wsf + 64;         // 384 floats
    float* B3    = wsf + 64 + NC * 96;
    float* buf   = wsf + 1024;
    const size_t VCs = (size_t)NC * VOL;
    float* a0 = buf;                 // z-conv outs; a0 reused as arg buffer
    float* a1 = buf + VCs;
    float* a2 = buf + 2 * VCs;
    float* Cn = buf + 3 * VCs;
    float* qb = buf + 4 * VCs;
    float* c0 = buf + 5 * VCs;       // z-conv of Cn, Cn^2
    float* c1 = buf + 6 * VCs;

    const dim3 gridZ(PLANE4 / 256, NSEGZ, NC);  // 9 x 12 x 4 = 432 blocks (256t)
    const dim3 gridYX(96 / YT, 96, NC);         // 6 x 96 x 4 = 2304 blocks (192t)
    const int gridV4 = VOL4 / 256;              // 864

    tables_kernel<<<1, 512, 0, stream>>>(sigma2, sigma3, taps2, taps3, B2, B3);
    softmax0_kernel<<<gridV4, 256, 0, stream>>>(o, eta, u);
    for (int it = 0; it < 10; it++) {
        pass1_z<<<gridZ, 256, 0, stream>>>(u, I, taps2, taps3, a0, a1, a2);
        pass2_yx<<<gridYX, TPBYX, 0, stream>>>(a0, a1, a2, taps2, taps3, B2, Cn, qb);
        pass4_z<<<gridZ, 256, 0, stream>>>(Cn, taps3, c0, c1);
        pass5_yx<<<gridYX, TPBYX, 0, stream>>>(c0, c1, qb, o, I, taps3, B3,
                                               eta, lam, mu, a0);
        pass6_softmax<<<gridV4, 256, 0, stream>>>(a0, u);
    }
}